// Round 1
// baseline (331.983 us; speedup 1.0000x reference)
//
#include <hip/hip_runtime.h>
#include <cstddef>

// Problem dims (fixed by setup_inputs)
#define Mdim 256     // batch B
#define Ndim 2048    // neurons N
#define Kdim 2048    // K (= N, W is NxN)
#define Tsteps 128   // time steps

// GEMM tiling
#define MT 64
#define NT 128
#define KT 16

// ---------------------------------------------------------------------------
// Kernel 1: partial fp32 GEMM  I_part[kb] = x[:, kchunk] @ W[kchunk, :]
// Written to ws[kb * M * N + ...]. No atomics -> deterministic order.
// For W = identity (the benchmark input) the result is bit-exact x regardless
// of summation order: off-diagonal products are +/-0 and acc + (+/-0) == acc.
// ---------------------------------------------------------------------------
__global__ __launch_bounds__(256) void gemm_part_kernel(
    const float* __restrict__ x, const float* __restrict__ W,
    float* __restrict__ ws, int KS)
{
    // +4 pads keep rows 16B-aligned and break 4-way write conflicts to 2-way
    __shared__ float As[KT][MT + 4];   // transposed: As[k][m]
    __shared__ float Bs[KT][NT + 4];   // Bs[k][n]

    const int tid = threadIdx.x;
    const int nb = blockIdx.x;   // 0..15
    const int mb = blockIdx.y;   // 0..3
    const int kb = blockIdx.z;   // 0..KS-1
    const int KC = Kdim / KS;
    const int k_begin = kb * KC;
    const int m0 = mb * MT;
    const int n0 = nb * NT;

    // compute-phase thread tile: 4 (m) x 8 (n), threads laid out 16(tm) x 16(tn)
    const int tn = tid & 15;     // n group: n = n0 + tn*8 .. +7
    const int tm = tid >> 4;     // m group: m = m0 + tm*4 .. +3

    // staging maps
    const int lm  = tid >> 2;          // A: 0..63 rows
    const int lk4 = (tid & 3) << 2;    // A: k offset 0,4,8,12
    const int bk  = tid >> 4;          // B: 0..15 k rows
    const int bn8 = (tid & 15) << 3;   // B: n offset 0..120

    float acc[4][8];
#pragma unroll
    for (int i = 0; i < 4; ++i)
#pragma unroll
        for (int j = 0; j < 8; ++j) acc[i][j] = 0.0f;

    for (int kt = k_begin; kt < k_begin + KC; kt += KT) {
        // global loads first (overlap with previous tile's compute)
        const float4 av  = *(const float4*)&x[(size_t)(m0 + lm) * Kdim + kt + lk4];
        const float4 bv0 = *(const float4*)&W[(size_t)(kt + bk) * Ndim + n0 + bn8];
        const float4 bv1 = *(const float4*)&W[(size_t)(kt + bk) * Ndim + n0 + bn8 + 4];
        __syncthreads();
        As[lk4 + 0][lm] = av.x;
        As[lk4 + 1][lm] = av.y;
        As[lk4 + 2][lm] = av.z;
        As[lk4 + 3][lm] = av.w;
        *(float4*)&Bs[bk][bn8]     = bv0;
        *(float4*)&Bs[bk][bn8 + 4] = bv1;
        __syncthreads();

#pragma unroll
        for (int kk = 0; kk < KT; ++kk) {
            const float4 a  = *(const float4*)&As[kk][tm * 4];
            const float4 b0 = *(const float4*)&Bs[kk][tn * 8];
            const float4 b1 = *(const float4*)&Bs[kk][tn * 8 + 4];
            const float aa[4] = {a.x, a.y, a.z, a.w};
            const float bb[8] = {b0.x, b0.y, b0.z, b0.w, b1.x, b1.y, b1.z, b1.w};
#pragma unroll
            for (int i = 0; i < 4; ++i)
#pragma unroll
                for (int j = 0; j < 8; ++j)
                    acc[i][j] = fmaf(aa[i], bb[j], acc[i][j]);
        }
    }

    float* wsp = ws + (size_t)kb * Mdim * Ndim;
#pragma unroll
    for (int i = 0; i < 4; ++i) {
        const int m = m0 + tm * 4 + i;
        float4 o0 = {acc[i][0], acc[i][1], acc[i][2], acc[i][3]};
        float4 o1 = {acc[i][4], acc[i][5], acc[i][6], acc[i][7]};
        *(float4*)&wsp[(size_t)m * Ndim + n0 + tn * 8]     = o0;
        *(float4*)&wsp[(size_t)m * Ndim + n0 + tn * 8 + 4] = o1;
    }
}

// ---------------------------------------------------------------------------
// Kernel 2: LIF rollout. One thread = 4 consecutive neurons (float4 stores).
// V_{t+1} = (ALPHA*V_t + I) * (1 - Z_t);  Z_{t+1} = (V_{t+1} >= 1)
// __fmul_rn/__fadd_rn forbid FMA contraction -> bit-match numpy's mul+add.
// ---------------------------------------------------------------------------
__global__ __launch_bounds__(256) void lif_sim_kernel(
    const float* __restrict__ ws, float* __restrict__ out, int KS)
{
    const int t4  = blockIdx.x * 256 + threadIdx.x;   // 0 .. B*N/4-1
    const int idx = t4 * 4;
    const int b = idx / Ndim;
    const int n = idx % Ndim;

    // Sum K-split partials in fixed order (exact for identity-W inputs).
    float4 I = *(const float4*)&ws[(size_t)b * Ndim + n];
    for (int ks = 1; ks < KS; ++ks) {
        const float4 p = *(const float4*)&ws[(size_t)ks * Mdim * Ndim + (size_t)b * Ndim + n];
        I.x = __fadd_rn(I.x, p.x);
        I.y = __fadd_rn(I.y, p.y);
        I.z = __fadd_rn(I.z, p.z);
        I.w = __fadd_rn(I.w, p.w);
    }
    const float Iv[4] = {I.x, I.y, I.z, I.w};

    // fp32(exp(-0.1) computed in f64) — matches numpy scalar promotion
    const float ALPHA = (float)0.9048374180359595;

    float V[4] = {0.0f, 0.0f, 0.0f, 0.0f};
    float Z[4] = {0.0f, 0.0f, 0.0f, 0.0f};

    float* op = out + (size_t)b * Tsteps * Ndim + n;
#pragma unroll 4
    for (int t = 0; t < Tsteps; ++t) {
#pragma unroll
        for (int j = 0; j < 4; ++j) {
            float v = __fmul_rn(ALPHA, V[j]);   // ALPHA * V
            v = __fadd_rn(v, Iv[j]);            // + I
            v = __fmul_rn(v, __fsub_rn(1.0f, Z[j]));  // * (1 - Z_prev)
            V[j] = v;
            Z[j] = (v >= 1.0f) ? 1.0f : 0.0f;
        }
        float4 s = {Z[0], Z[1], Z[2], Z[3]};
        *(float4*)&op[(size_t)t * Ndim] = s;
    }
}

// ---------------------------------------------------------------------------
extern "C" void kernel_launch(void* const* d_in, const int* in_sizes, int n_in,
                              void* d_out, int out_size, void* d_ws, size_t ws_size,
                              hipStream_t stream) {
    const float* x = (const float*)d_in[0];   // [256, 2048] fp32
    const float* W = (const float*)d_in[1];   // [2048, 2048] fp32
    float* out = (float*)d_out;               // [256, 128, 2048] fp32
    float* ws  = (float*)d_ws;

    const size_t plane = (size_t)Mdim * Ndim * sizeof(float);  // 2 MB
    int KS = 1;
    if (ws_size >= 4 * plane)      KS = 4;   // 256 blocks -> 1/CU
    else if (ws_size >= 2 * plane) KS = 2;

    dim3 ggrid(Ndim / NT, Mdim / MT, KS);
    gemm_part_kernel<<<ggrid, 256, 0, stream>>>(x, W, ws, KS);

    const int sim_threads = Mdim * Ndim / 4;  // 131072
    lif_sim_kernel<<<dim3(sim_threads / 256), 256, 0, stream>>>(ws, out, KS);
}

// Round 3
// 302.061 us; speedup vs baseline: 1.0991x; 1.0991x over previous
//
#include <hip/hip_runtime.h>
#include <cstddef>

// Problem dims (fixed by setup_inputs)
#define Mdim 256     // batch B
#define Ndim 2048    // neurons N
#define Kdim 2048    // K (= N, W is NxN)
#define Tsteps 128   // time steps

// GEMM tiling: 128x128 block tile, 8x8 thread tile, 256 threads (16x16)
#define MT 128
#define NT 128
#define KT 16

// native clang vector type — accepted by __builtin_nontemporal_store
typedef float v4f __attribute__((ext_vector_type(4)));

// ---------------------------------------------------------------------------
// Kernel 1: partial fp32 GEMM  ws[kb] = x[:, kchunk] @ W[kchunk, :]
// KS-way K-split -> 16*2*16 = 512 blocks = 2 blocks/CU (8 waves/CU) so one
// block's compute covers the other's barrier drain. No atomics.
// For W = identity (the benchmark input) the result is bit-exact x for any
// summation order: off-diagonal products are +/-0 and acc + (+/-0) == acc.
// ---------------------------------------------------------------------------
__global__ __launch_bounds__(256, 2) void gemm_part_kernel(
    const float* __restrict__ x, const float* __restrict__ W,
    float* __restrict__ ws, int KS)
{
    // +4 pad => read bank-quads: A (kk*33 + tm*2)%8 -> 4 distinct, broadcast;
    // B (kk*33 + tn)%8 -> 8 quads x 2-way = free (m136: 2-way is free)
    __shared__ float As[KT][MT + 4];   // transposed: As[k][m]
    __shared__ float Bs[KT][NT + 4];   // Bs[k][n]

    const int tid = threadIdx.x;
    const int nb = blockIdx.x;        // 0..15
    const int mb = blockIdx.y;        // 0..1
    const int kb = blockIdx.z;        // 0..KS-1
    const int KC = Kdim / KS;
    const int ntiles = KC / KT;
    const int k_begin = kb * KC;
    const int m0 = mb * MT;
    const int n0 = nb * NT;

    // staging maps: A = 128 rows x 16 k (2 float4/thread along k, transposed
    // store => 2-way write conflict = free); B = 16 k x 128 n (2 float4/thread)
    const int am = tid >> 1;            // 0..127
    const int ak = (tid & 1) * 8;       // 0 or 8
    const int bk = tid >> 4;            // 0..15
    const int bn = (tid & 15) * 8;      // 0..120

    // compute maps: m = m0 + tm*8 + i (i<8), n = n0 + tn*4 + j and +64 (j<4)
    const int tn = tid & 15;
    const int tm = tid >> 4;            // 0..15

    const float* xrow = x + (size_t)(m0 + am) * Kdim + k_begin + ak;
    const float* wrow = W + (size_t)(k_begin + bk) * Ndim + n0 + bn;

    // prefetch tile 0
    float4 av0 = *(const float4*)(xrow);
    float4 av1 = *(const float4*)(xrow + 4);
    float4 bv0 = *(const float4*)(wrow);
    float4 bv1 = *(const float4*)(wrow + 4);

    float acc[8][8];
#pragma unroll
    for (int i = 0; i < 8; ++i)
#pragma unroll
        for (int j = 0; j < 8; ++j) acc[i][j] = 0.0f;

    for (int t = 0; t < ntiles; ++t) {
        if (t > 0) __syncthreads();       // LDS free (prev compute done)
        As[ak + 0][am] = av0.x;
        As[ak + 1][am] = av0.y;
        As[ak + 2][am] = av0.z;
        As[ak + 3][am] = av0.w;
        As[ak + 4][am] = av1.x;
        As[ak + 5][am] = av1.y;
        As[ak + 6][am] = av1.z;
        As[ak + 7][am] = av1.w;
        *(float4*)&Bs[bk][bn]     = bv0;
        *(float4*)&Bs[bk][bn + 4] = bv1;
        __syncthreads();                  // LDS visible

        // issue next tile's global loads AFTER the barrier: they fly during
        // the ~6K-cycle compute below; the vmcnt drain at the next barrier
        // is then already satisfied.
        if (t + 1 < ntiles) {
            const float* xn = xrow + (size_t)(t + 1) * KT;
            const float* wn = wrow + (size_t)(t + 1) * KT * Ndim;
            av0 = *(const float4*)(xn);
            av1 = *(const float4*)(xn + 4);
            bv0 = *(const float4*)(wn);
            bv1 = *(const float4*)(wn + 4);
        }

#pragma unroll 8
        for (int kk = 0; kk < KT; ++kk) {
            const float4 a0 = *(const float4*)&As[kk][tm * 8];
            const float4 a1 = *(const float4*)&As[kk][tm * 8 + 4];
            const float4 b0 = *(const float4*)&Bs[kk][tn * 4];
            const float4 b1 = *(const float4*)&Bs[kk][tn * 4 + 64];
            const float aa[8] = {a0.x, a0.y, a0.z, a0.w, a1.x, a1.y, a1.z, a1.w};
            const float bb[8] = {b0.x, b0.y, b0.z, b0.w, b1.x, b1.y, b1.z, b1.w};
#pragma unroll
            for (int i = 0; i < 8; ++i)
#pragma unroll
                for (int j = 0; j < 8; ++j)
                    acc[i][j] = fmaf(aa[i], bb[j], acc[i][j]);
        }
    }

    float* wsp = ws + (size_t)kb * Mdim * Ndim;
#pragma unroll
    for (int i = 0; i < 8; ++i) {
        const int m = m0 + tm * 8 + i;
        float4 o0 = {acc[i][0], acc[i][1], acc[i][2], acc[i][3]};
        float4 o1 = {acc[i][4], acc[i][5], acc[i][6], acc[i][7]};
        *(float4*)&wsp[(size_t)m * Ndim + n0 + tn * 4]      = o0;
        *(float4*)&wsp[(size_t)m * Ndim + n0 + tn * 4 + 64] = o1;
    }
}

// ---------------------------------------------------------------------------
// Kernel 2: LIF rollout. One thread = 4 consecutive neurons (float4 stores).
// V_{t+1} = (ALPHA*V_t + I) * (1 - Z_t);  Z_{t+1} = (V_{t+1} >= 1)
// __fmul_rn/__fadd_rn forbid FMA contraction -> bit-match numpy's mul+add.
// Output (268 MB, write-once) uses nontemporal stores.
// ---------------------------------------------------------------------------
__global__ __launch_bounds__(256) void lif_sim_kernel(
    const float* __restrict__ ws, float* __restrict__ out, int KS)
{
    const int t4  = blockIdx.x * 256 + threadIdx.x;   // 0 .. B*N/4-1
    const int idx = t4 * 4;
    const int b = idx / Ndim;
    const int n = idx % Ndim;

    // Sum K-split partials in fixed order (exact for identity-W inputs).
    float4 I = *(const float4*)&ws[(size_t)b * Ndim + n];
    for (int ks = 1; ks < KS; ++ks) {
        const float4 p = *(const float4*)&ws[(size_t)ks * Mdim * Ndim + (size_t)b * Ndim + n];
        I.x = __fadd_rn(I.x, p.x);
        I.y = __fadd_rn(I.y, p.y);
        I.z = __fadd_rn(I.z, p.z);
        I.w = __fadd_rn(I.w, p.w);
    }
    const float Iv[4] = {I.x, I.y, I.z, I.w};

    // fp32(exp(-0.1) computed in f64) — matches numpy scalar promotion
    const float ALPHA = (float)0.9048374180359595;

    float V[4] = {0.0f, 0.0f, 0.0f, 0.0f};
    float Z[4] = {0.0f, 0.0f, 0.0f, 0.0f};

    float* op = out + (size_t)b * Tsteps * Ndim + n;
#pragma unroll 4
    for (int t = 0; t < Tsteps; ++t) {
#pragma unroll
        for (int j = 0; j < 4; ++j) {
            float v = __fmul_rn(ALPHA, V[j]);          // ALPHA * V
            v = __fadd_rn(v, Iv[j]);                   // + I
            v = __fmul_rn(v, __fsub_rn(1.0f, Z[j]));   // * (1 - Z_prev)
            V[j] = v;
            Z[j] = (v >= 1.0f) ? 1.0f : 0.0f;
        }
        v4f s = {Z[0], Z[1], Z[2], Z[3]};
        __builtin_nontemporal_store(s, (v4f*)&op[(size_t)t * Ndim]);
    }
}

// ---------------------------------------------------------------------------
extern "C" void kernel_launch(void* const* d_in, const int* in_sizes, int n_in,
                              void* d_out, int out_size, void* d_ws, size_t ws_size,
                              hipStream_t stream) {
    const float* x = (const float*)d_in[0];   // [256, 2048] fp32
    const float* W = (const float*)d_in[1];   // [2048, 2048] fp32
    float* out = (float*)d_out;               // [256, 128, 2048] fp32
    float* ws  = (float*)d_ws;

    const size_t plane = (size_t)Mdim * Ndim * sizeof(float);  // 2 MB
    int KS = 1;
    if (ws_size >= 16 * plane)     KS = 16;  // 512 blocks -> 2/CU
    else if (ws_size >= 8 * plane) KS = 8;
    else if (ws_size >= 4 * plane) KS = 4;
    else if (ws_size >= 2 * plane) KS = 2;

    dim3 ggrid(Ndim / NT, Mdim / MT, KS);
    gemm_part_kernel<<<ggrid, 256, 0, stream>>>(x, W, ws, KS);

    const int sim_threads = Mdim * Ndim / 4;  // 131072
    lif_sim_kernel<<<dim3(sim_threads / 256), 256, 0, stream>>>(ws, out, KS);
}

// Round 4
// 293.807 us; speedup vs baseline: 1.1299x; 1.0281x over previous
//
#include <hip/hip_runtime.h>
#include <cstddef>

// Problem dims (fixed by setup_inputs)
#define Mdim 256     // batch B
#define Ndim 2048    // neurons N
#define Kdim 2048    // K (= N, W is NxN)
#define Tsteps 128   // time steps

// GEMM tiling: 128x128 block tile, 8x8 thread tile, 256 threads (16x16)
#define MT 128
#define NT 128
#define KT 16

// native clang vector type — accepted by __builtin_nontemporal_store
typedef float v4f __attribute__((ext_vector_type(4)));

// ---------------------------------------------------------------------------
// Kernel 1: partial fp32 GEMM  ws[kb] = x[:, kchunk] @ W[kchunk, :]
// Double-buffered LDS (1 barrier/iter) + block-level ZERO-TILE SKIP: after
// staging a 16x128 B-tile, a ballot across the block detects all-zero tiles
// and skips the LDS-read+FMA loop (contribution is exactly +0; spikes are
// insensitive to +/-0). For W=eye only 8/128 K-tiles per n-column are
// nonzero, so the kernel is staging-bound and fast even at KS=1 (2MB ws).
// No atomics -> deterministic; K-order is bit-exact for identity-W inputs
// (off-diagonal products are +/-0 and acc + (+/-0) == acc).
// ---------------------------------------------------------------------------
__global__ __launch_bounds__(256, 2) void gemm_part_kernel(
    const float* __restrict__ x, const float* __restrict__ W,
    float* __restrict__ ws, int KS)
{
    __shared__ float As[2][KT][MT + 4];   // transposed: As[buf][k][m]
    __shared__ float Bs[2][KT][NT + 4];   // Bs[buf][k][n]
    __shared__ int nzf[2][4] __attribute__((aligned(16)));  // per-wave nz flags

    const int tid = threadIdx.x;
    const int nb = blockIdx.x;        // 0..15
    const int mb = blockIdx.y;        // 0..1
    const int kb = blockIdx.z;        // 0..KS-1
    const int KC = Kdim / KS;
    const int ntiles = KC / KT;
    const int k_begin = kb * KC;
    const int m0 = mb * MT;
    const int n0 = nb * NT;
    const int wave = tid >> 6;

    // staging maps: A = 128 rows x 16 k (8 floats along k, transposed store);
    // B = 16 k x 128 n (2 float4/thread)
    const int am = tid >> 1;            // 0..127
    const int ak = (tid & 1) * 8;       // 0 or 8
    const int bk = tid >> 4;            // 0..15
    const int bn = (tid & 15) * 8;      // 0..120

    // compute maps: m = m0 + tm*8 + i (i<8), n = n0 + tn*4 + j and +64 (j<4)
    const int tn = tid & 15;
    const int tm = tid >> 4;            // 0..15

    const float* xrow = x + (size_t)(m0 + am) * Kdim + k_begin + ak;
    const float* wrow = W + (size_t)(k_begin + bk) * Ndim + n0 + bn;

    // ---- pre-loop: load + stage tile 0 into buf 0 ----
    float4 av0 = *(const float4*)(xrow);
    float4 av1 = *(const float4*)(xrow + 4);
    float4 bv0 = *(const float4*)(wrow);
    float4 bv1 = *(const float4*)(wrow + 4);

    As[0][ak + 0][am] = av0.x;  As[0][ak + 1][am] = av0.y;
    As[0][ak + 2][am] = av0.z;  As[0][ak + 3][am] = av0.w;
    As[0][ak + 4][am] = av1.x;  As[0][ak + 5][am] = av1.y;
    As[0][ak + 6][am] = av1.z;  As[0][ak + 7][am] = av1.w;
    *(float4*)&Bs[0][bk][bn]     = bv0;
    *(float4*)&Bs[0][bk][bn + 4] = bv1;
    {
        const bool nz = (bv0.x != 0.0f) | (bv0.y != 0.0f) | (bv0.z != 0.0f) |
                        (bv0.w != 0.0f) | (bv1.x != 0.0f) | (bv1.y != 0.0f) |
                        (bv1.z != 0.0f) | (bv1.w != 0.0f);
        const unsigned long long m = __ballot(nz);
        if ((tid & 63) == 0) nzf[0][wave] = (m != 0ull) ? 1 : 0;
    }
    // prefetch tile 1
    if (1 < ntiles) {
        av0 = *(const float4*)(xrow + KT);
        av1 = *(const float4*)(xrow + KT + 4);
        bv0 = *(const float4*)(wrow + (size_t)KT * Ndim);
        bv1 = *(const float4*)(wrow + (size_t)KT * Ndim + 4);
    }
    __syncthreads();

    float acc[8][8];
#pragma unroll
    for (int i = 0; i < 8; ++i)
#pragma unroll
        for (int j = 0; j < 8; ++j) acc[i][j] = 0.0f;

    for (int t = 0; t < ntiles; ++t) {
        const int cur = t & 1;
        const int nxt = cur ^ 1;

        // stage tile t+1 into the other buffer (no conflict with reads of cur)
        if (t + 1 < ntiles) {
            As[nxt][ak + 0][am] = av0.x;  As[nxt][ak + 1][am] = av0.y;
            As[nxt][ak + 2][am] = av0.z;  As[nxt][ak + 3][am] = av0.w;
            As[nxt][ak + 4][am] = av1.x;  As[nxt][ak + 5][am] = av1.y;
            As[nxt][ak + 6][am] = av1.z;  As[nxt][ak + 7][am] = av1.w;
            *(float4*)&Bs[nxt][bk][bn]     = bv0;
            *(float4*)&Bs[nxt][bk][bn + 4] = bv1;
            const bool nz = (bv0.x != 0.0f) | (bv0.y != 0.0f) | (bv0.z != 0.0f) |
                            (bv0.w != 0.0f) | (bv1.x != 0.0f) | (bv1.y != 0.0f) |
                            (bv1.z != 0.0f) | (bv1.w != 0.0f);
            const unsigned long long m = __ballot(nz);
            if ((tid & 63) == 0) nzf[nxt][wave] = (m != 0ull) ? 1 : 0;
        }

        // issue loads for tile t+2 (fly during compute below)
        if (t + 2 < ntiles) {
            const float* xn = xrow + (size_t)(t + 2) * KT;
            const float* wn = wrow + (size_t)(t + 2) * KT * Ndim;
            av0 = *(const float4*)(xn);
            av1 = *(const float4*)(xn + 4);
            bv0 = *(const float4*)(wn);
            bv1 = *(const float4*)(wn + 4);
        }

        // gate: was tile t's B entirely zero? (flags published by last barrier)
        const int4 f = *(const int4*)&nzf[cur][0];
        if (f.x | f.y | f.z | f.w) {
#pragma unroll 8
            for (int kk = 0; kk < KT; ++kk) {
                const float4 a0 = *(const float4*)&As[cur][kk][tm * 8];
                const float4 a1 = *(const float4*)&As[cur][kk][tm * 8 + 4];
                const float4 b0 = *(const float4*)&Bs[cur][kk][tn * 4];
                const float4 b1 = *(const float4*)&Bs[cur][kk][tn * 4 + 64];
                const float aa[8] = {a0.x, a0.y, a0.z, a0.w, a1.x, a1.y, a1.z, a1.w};
                const float bb[8] = {b0.x, b0.y, b0.z, b0.w, b1.x, b1.y, b1.z, b1.w};
#pragma unroll
                for (int i = 0; i < 8; ++i)
#pragma unroll
                    for (int j = 0; j < 8; ++j)
                        acc[i][j] = fmaf(aa[i], bb[j], acc[i][j]);
            }
        }
        __syncthreads();   // publishes tile t+1's staging for next iteration
    }

    float* wsp = ws + (size_t)kb * Mdim * Ndim;
#pragma unroll
    for (int i = 0; i < 8; ++i) {
        const int m = m0 + tm * 8 + i;
        float4 o0 = {acc[i][0], acc[i][1], acc[i][2], acc[i][3]};
        float4 o1 = {acc[i][4], acc[i][5], acc[i][6], acc[i][7]};
        *(float4*)&wsp[(size_t)m * Ndim + n0 + tn * 4]      = o0;
        *(float4*)&wsp[(size_t)m * Ndim + n0 + tn * 4 + 64] = o1;
    }
}

// ---------------------------------------------------------------------------
// Kernel 2: LIF rollout. One thread = 4 consecutive neurons (float4 stores).
// V_{t+1} = (ALPHA*V_t + I) * (1 - Z_t);  Z_{t+1} = (V_{t+1} >= 1)
// __fmul_rn/__fadd_rn forbid FMA contraction -> bit-match numpy's mul+add.
// Output (268 MB, write-once) uses nontemporal stores.
// ---------------------------------------------------------------------------
__global__ __launch_bounds__(256) void lif_sim_kernel(
    const float* __restrict__ ws, float* __restrict__ out, int KS)
{
    const int t4  = blockIdx.x * 256 + threadIdx.x;   // 0 .. B*N/4-1
    const int idx = t4 * 4;
    const int b = idx / Ndim;
    const int n = idx % Ndim;

    // Sum K-split partials in fixed order (exact for identity-W inputs).
    float4 I = *(const float4*)&ws[(size_t)b * Ndim + n];
    for (int ks = 1; ks < KS; ++ks) {
        const float4 p = *(const float4*)&ws[(size_t)ks * Mdim * Ndim + (size_t)b * Ndim + n];
        I.x = __fadd_rn(I.x, p.x);
        I.y = __fadd_rn(I.y, p.y);
        I.z = __fadd_rn(I.z, p.z);
        I.w = __fadd_rn(I.w, p.w);
    }
    const float Iv[4] = {I.x, I.y, I.z, I.w};

    // fp32(exp(-0.1) computed in f64) — matches numpy scalar promotion
    const float ALPHA = (float)0.9048374180359595;

    float V[4] = {0.0f, 0.0f, 0.0f, 0.0f};
    float Z[4] = {0.0f, 0.0f, 0.0f, 0.0f};

    float* op = out + (size_t)b * Tsteps * Ndim + n;
#pragma unroll 4
    for (int t = 0; t < Tsteps; ++t) {
#pragma unroll
        for (int j = 0; j < 4; ++j) {
            float v = __fmul_rn(ALPHA, V[j]);          // ALPHA * V
            v = __fadd_rn(v, Iv[j]);                   // + I
            v = __fmul_rn(v, __fsub_rn(1.0f, Z[j]));   // * (1 - Z_prev)
            V[j] = v;
            Z[j] = (v >= 1.0f) ? 1.0f : 0.0f;
        }
        v4f s = {Z[0], Z[1], Z[2], Z[3]};
        __builtin_nontemporal_store(s, (v4f*)&op[(size_t)t * Ndim]);
    }
}

// ---------------------------------------------------------------------------
extern "C" void kernel_launch(void* const* d_in, const int* in_sizes, int n_in,
                              void* d_out, int out_size, void* d_ws, size_t ws_size,
                              hipStream_t stream) {
    const float* x = (const float*)d_in[0];   // [256, 2048] fp32
    const float* W = (const float*)d_in[1];   // [2048, 2048] fp32
    float* out = (float*)d_out;               // [256, 128, 2048] fp32
    float* ws  = (float*)d_ws;

    const size_t plane = (size_t)Mdim * Ndim * sizeof(float);  // 2 MB
    int KS = 1;
    if (ws_size >= 16 * plane)     KS = 16;  // 512 blocks -> 2/CU
    else if (ws_size >= 8 * plane) KS = 8;
    else if (ws_size >= 4 * plane) KS = 4;
    else if (ws_size >= 2 * plane) KS = 2;

    dim3 ggrid(Ndim / NT, Mdim / MT, KS);
    gemm_part_kernel<<<ggrid, 256, 0, stream>>>(x, W, ws, KS);

    const int sim_threads = Mdim * Ndim / 4;  // 131072
    lif_sim_kernel<<<dim3(sim_threads / 256), 256, 0, stream>>>(ws, out, KS);
}